// Round 1
// baseline (345.592 us; speedup 1.0000x reference)
//
#include <hip/hip_runtime.h>

typedef _Float16 half8 __attribute__((ext_vector_type(8)));
typedef _Float16 half4v __attribute__((ext_vector_type(4)));
typedef float floatx4 __attribute__((ext_vector_type(4)));

#define C_DIM 256
#define M_DIM 512
#define HW 4096
#define TAU 0.0025f
#define LCAP 16

// ---------------- prep: memN = l2norm(relu(relu(mem@w1+b1)@w2+b2)) ----------------
// R11: fill grid widened 512x128 -> 2048x256 (att_map 134 MB zero-fill was running at
// 4 waves/CU = occupancy-starved for a pure-BW stream). Every block fills a contiguous
// 64 KB slice with nontemporal float4 stores (keeps x resident in L3 for main_kernel);
// blocks 0..511 additionally run the MLP with the ORIGINAL 128-thread arithmetic
// (bit-identical reduction order -> preserves the absmax==0.0 survivor selection).
__global__ __launch_bounds__(256) void prep_kernel(
    const float* __restrict__ memory, const float* __restrict__ w1,
    const float* __restrict__ b1, const float* __restrict__ w2,
    const float* __restrict__ b2,
    _Float16* __restrict__ mN, float* __restrict__ mN32,
    float* __restrict__ attmap)
{
  __shared__ float sm[256];
  __shared__ float sh[128];
  __shared__ float s_part[2];
  __shared__ float s_tot;
  const int r = blockIdx.x;   // 0..2047
  const int t = threadIdx.x;  // 0..255

  // ---- att_map zero-fill: 2048 blocks x 256 thr x 16 float4 = 134 MB, coalesced
  {
    const floatx4 z = {0.f, 0.f, 0.f, 0.f};
    floatx4* p4 = (floatx4*)attmap + (size_t)r * 4096 + t;
#pragma unroll
    for (int k = 0; k < 16; ++k) __builtin_nontemporal_store(z, p4 + k * 256);
  }
  if (r >= M_DIM) return;

  if (t < 128) {
    sm[t]       = memory[r * C_DIM + t];
    sm[t + 128] = memory[r * C_DIM + t + 128];
  }
  __syncthreads();
  float o0 = 0.f, o1 = 0.f;
  if (t < 128) {
    float acc = b1[t];
#pragma unroll 8
    for (int c = 0; c < 256; ++c) acc = fmaf(sm[c], w1[c * 128 + t], acc);
    sh[t] = fmaxf(acc, 0.f);
  }
  __syncthreads();
  if (t < 128) {
    o0 = b2[t];
    o1 = b2[t + 128];
#pragma unroll 8
    for (int k = 0; k < 128; ++k) {
      float h = sh[k];
      o0 = fmaf(h, w2[k * 256 + t], o0);
      o1 = fmaf(h, w2[k * 256 + t + 128], o1);
    }
    o0 = fmaxf(o0, 0.f);
    o1 = fmaxf(o1, 0.f);
    float ss = o0 * o0 + o1 * o1;
#pragma unroll
    for (int off = 32; off >= 1; off >>= 1) ss += __shfl_down(ss, off);
    if ((t & 63) == 0) s_part[t >> 6] = ss;
  }
  __syncthreads();
  if (t == 0) s_tot = s_part[0] + s_part[1];
  __syncthreads();
  if (t < 128) {
    const float inv = 1.f / fmaxf(sqrtf(s_tot), 1e-12f);
    const float v0 = o0 * inv, v1 = o1 * inv;
    mN[r * C_DIM + t]        = (_Float16)v0;
    mN[r * C_DIM + t + 128]  = (_Float16)v1;
    mN32[r * C_DIM + t]       = v0;
    mN32[r * C_DIM + t + 128] = v1;
  }
}

#define MFMA16(a, b, c) __builtin_amdgcn_mfma_f32_16x16x32_f16(a, b, c, 0, 0, 0)

// ---------------- fused main kernel: 32 pixels per block, 2048 blocks ----------------
// R11 restructure: the old 64-px tile needed acc[4][4] = 64 AGPR + 64 arch VGPR = 128
// regs/wave -> hard cap at 4 waves/SIMD (and 71.7 KB LDS -> 2 blocks/CU); measured
// occupancy 43% with every pipe <25% busy = latency-bound with no TLP headroom.
// 32-px tile: acc[2][4] = 32 AGPR, LDS 20480 B, __launch_bounds__(512,6) -> 3 blocks/CU
// (24 waves/CU). B loads single-buffered (the unrolled kb loop lets the compiler
// pipeline within the 6-wave register budget); extra TLP hides the L2 B-latency.
// Per-output arithmetic (MFMA fragments, reduction orders) is unchanged vs R10.
__global__ __launch_bounds__(512, 6) void main_kernel(
    const float* __restrict__ x,
    const _Float16* __restrict__ mN,
    const float* __restrict__ mN32,
    float* __restrict__ out, float* __restrict__ attmap)
{
  __shared__ _Float16       Xh[32][264];       // 16896 B
  __shared__ unsigned short s_lslot[32][LCAP]; // 1024 B
  __shared__ float          s_lval[32][LCAP];  // 2048 B
  __shared__ int      s_cnt[32];
  __shared__ float    s_sumsq[32];
  __shared__ float    s_sum1[32];
  __shared__ float    s_sum2[32];               // total 20480 B

  const int tid  = threadIdx.x;
  const int wave = tid >> 6;     // 0..7
  const int lane = tid & 63;
  const int q    = lane >> 4;    // quad within wave
  const int c16  = lane & 15;
  const int g    = tid >> 3;     // 0..63: channel quad for phase A
  const int pxq  = tid & 7;      // pixel quad for phase A

  const int blk = blockIdx.x;          // 2048 blocks
  const int img = blk >> 7;            // 128 blocks per image
  const int hw0 = (blk & 127) * 32;
  const float* __restrict__ xb = x + (size_t)img * C_DIM * HW + hw0;

  if (tid < 32) {
    s_sumsq[tid] = 0.f; s_sum1[tid] = 0.f; s_sum2[tid] = 0.f; s_cnt[tid] = 0;
  }
  __syncthreads();  // B0

  // ---- Phase A: float4 loads (4 ch x 4 px per thread), fp16 pack, sumsq
  {
    floatx4 v[4];
#pragma unroll
    for (int i = 0; i < 4; ++i)
      v[i] = *(const floatx4*)(xb + (size_t)(4 * g + i) * HW + pxq * 4);
    float ps[4];
#pragma unroll
    for (int j = 0; j < 4; ++j) {
      const int p = pxq * 4 + j;
      half4v hv = {(_Float16)v[0][j], (_Float16)v[1][j], (_Float16)v[2][j], (_Float16)v[3][j]};
      *(half4v*)&Xh[p][4 * g] = hv;
      ps[j] = v[0][j] * v[0][j] + v[1][j] * v[1][j] + v[2][j] * v[2][j] + v[3][j] * v[3][j];
    }
#pragma unroll
    for (int off = 8; off < 64; off <<= 1)
#pragma unroll
      for (int j = 0; j < 4; ++j) ps[j] += __shfl_xor(ps[j], off);
    if ((lane >> 3) == 0) {
#pragma unroll
      for (int j = 0; j < 4; ++j) atomicAdd(&s_sumsq[4 * (lane & 7) + j], ps[j]);
    }
  }

  // B base pointers (kb offsets fold into the 13-bit imm: kb*32 halves = 64..448 B)
  const _Float16* bp[4];
#pragma unroll
  for (int nt = 0; nt < 4; ++nt)
    bp[nt] = mN + (size_t)(wave * 64 + nt * 16 + c16) * C_DIM + q * 8;

  __syncthreads();  // B1: Xh + sumsq ready

  // ---- Phase B: GEMM1  S[32][512] = Xh @ mN^T  (fp16 MFMA)
  floatx4 acc[2][4];
#pragma unroll
  for (int mt = 0; mt < 2; ++mt)
#pragma unroll
    for (int nt = 0; nt < 4; ++nt) {
      floatx4 z = {0.f, 0.f, 0.f, 0.f};
      acc[mt][nt] = z;
    }
#pragma unroll
  for (int kb = 0; kb < 8; ++kb) {
    half8 bv[4];
#pragma unroll
    for (int nt = 0; nt < 4; ++nt) bv[nt] = *(const half8*)(bp[nt] + kb * 32);
    const int k0 = kb * 32 + q * 8;
    half8 a0 = *(const half8*)&Xh[c16][k0];
    half8 a1 = *(const half8*)&Xh[16 + c16][k0];
#pragma unroll
    for (int nt = 0; nt < 4; ++nt) {
      acc[0][nt] = MFMA16(a0, bv[nt], acc[0][nt]);
      acc[1][nt] = MFMA16(a1, bv[nt], acc[1][nt]);
    }
  }

  // ---- Phase C: scale by 1/||x||, exp (cosines in [-1,1], no max shift needed)
  // C/D layout: value (m = mt*16 + q*4 + r, n = wave*64 + nt*16 + c16)
#pragma unroll
  for (int mt = 0; mt < 2; ++mt)
#pragma unroll
    for (int r = 0; r < 4; ++r) {
      const int m = mt * 16 + q * 4 + r;
      const float iv = 1.f / fmaxf(sqrtf(s_sumsq[m]), 1e-12f);
      float s = 0.f;
#pragma unroll
      for (int nt = 0; nt < 4; ++nt) {
        const float e = __expf(acc[mt][nt][r] * iv);
        acc[mt][nt][r] = e;
        s += e;
      }
      s += __shfl_xor(s, 1);
      s += __shfl_xor(s, 2);
      s += __shfl_xor(s, 4);
      s += __shfl_xor(s, 8);
      if (c16 == 0) atomicAdd(&s_sum1[m], s);
    }
  __syncthreads();  // B2: softmax denominators ready

  // t = relu(p - tau); row sum of t
#pragma unroll
  for (int mt = 0; mt < 2; ++mt)
#pragma unroll
    for (int r = 0; r < 4; ++r) {
      const int m = mt * 16 + q * 4 + r;
      const float isum = 1.f / s_sum1[m];
      float s = 0.f;
#pragma unroll
      for (int nt = 0; nt < 4; ++nt) {
        const float tv = fmaxf(acc[mt][nt][r] * isum - TAU, 0.f);
        acc[mt][nt][r] = tv;
        s += tv;
      }
      s += __shfl_xor(s, 1);
      s += __shfl_xor(s, 2);
      s += __shfl_xor(s, 4);
      s += __shfl_xor(s, 8);
      if (c16 == 0) atomicAdd(&s_sum2[m], s);
    }
  __syncthreads();  // B3: shrink sums ready

  // ---- normalize att in regs; emit nonzeros to per-pixel lists AND scatter the
  //      (rare) fp32 values straight into the pre-zeroed att_map.
#pragma unroll
  for (int mt = 0; mt < 2; ++mt) {
    float rs[4];
#pragma unroll
    for (int r = 0; r < 4; ++r)
      rs[r] = 1.f / fmaxf(s_sum2[mt * 16 + q * 4 + r], 1e-12f);
#pragma unroll
    for (int nt = 0; nt < 4; ++nt) {
      floatx4 a4 = acc[mt][nt];
      const unsigned n = wave * 64 + nt * 16 + c16;
#pragma unroll
      for (int r = 0; r < 4; ++r) {
        a4[r] *= rs[r];
        if (a4[r] > 0.f) {
          const int m = mt * 16 + q * 4 + r;
          const int idx = atomicAdd(&s_cnt[m], 1);
          if (idx < LCAP) {
            s_lslot[m][idx] = (unsigned short)n;
            s_lval[m][idx]  = a4[r];
          }
          attmap[((size_t)img * M_DIM + n) * HW + hw0 + m] = a4[r];
        }
      }
    }
  }
  __syncthreads();  // B4: lists ready

  // ---- sparse gather: thread owns 4 consecutive pixels x 4 channels.
  // All loads precede all stores (R6 lesson).
  const int px4 = (tid & 7) * 4;    // pixels px4..px4+3
  const int chg = tid >> 3;         // 0..63 -> channels [4*chg, 4*chg+4)
  floatx4 f[4] = {{0.f,0.f,0.f,0.f},{0.f,0.f,0.f,0.f},{0.f,0.f,0.f,0.f},{0.f,0.f,0.f,0.f}};
#pragma unroll
  for (int p = 0; p < 4; ++p) {
    const int cn = min(s_cnt[px4 + p], LCAP);
    for (int j = 0; j < cn; ++j) {
      const int slot  = s_lslot[px4 + p][j];
      const float v   = s_lval[px4 + p][j];
      const floatx4 r0 = *(const floatx4*)(mN32 + (size_t)slot * C_DIM + chg * 4);
      f[0][p] += v * r0[0]; f[1][p] += v * r0[1];
      f[2][p] += v * r0[2]; f[3][p] += v * r0[3];
    }
  }

  // ---- out stores: float4 per (channel, 4-px group); nontemporal (write-once)
#pragma unroll
  for (int c = 0; c < 4; ++c)
    __builtin_nontemporal_store(
        f[c], (floatx4*)(out + ((size_t)img * C_DIM + chg * 4 + c) * HW + hw0 + px4));
}

extern "C" void kernel_launch(void* const* d_in, const int* in_sizes, int n_in,
                              void* d_out, int out_size, void* d_ws, size_t ws_size,
                              hipStream_t stream) {
  (void)in_sizes; (void)n_in; (void)out_size; (void)ws_size;
  const float* x      = (const float*)d_in[0];
  const float* memory = (const float*)d_in[1];
  const float* w1     = (const float*)d_in[2];
  const float* b1     = (const float*)d_in[3];
  const float* w2     = (const float*)d_in[4];
  const float* b2     = (const float*)d_in[5];
  float* out    = (float*)d_out;
  float* attmap = out + (size_t)16 * C_DIM * HW;  // output first, att_map second

  _Float16* mN   = (_Float16*)d_ws;
  float*    mN32 = (float*)((char*)d_ws + (size_t)M_DIM * C_DIM * sizeof(_Float16));

  hipLaunchKernelGGL(prep_kernel, dim3(2048), dim3(256), 0, stream,
                     memory, w1, b1, w2, b2, mN, mN32, attmap);
  hipLaunchKernelGGL(main_kernel, dim3(2048), dim3(512), 0, stream,
                     x, mN, mN32, out, attmap);
}

// Round 2
// 343.357 us; speedup vs baseline: 1.0065x; 1.0065x over previous
//
#include <hip/hip_runtime.h>

typedef _Float16 half8 __attribute__((ext_vector_type(8)));
typedef _Float16 half4v __attribute__((ext_vector_type(4)));
typedef float floatx4 __attribute__((ext_vector_type(4)));

#define C_DIM 256
#define M_DIM 512
#define HW 4096
#define TAU 0.0025f
#define LCAP 16

// ---------------- prep: memN = l2norm(relu(relu(mem@w1+b1)@w2+b2)) ----------------
// R12: att_map zero-fill REMOVED (main_kernel now dense-stores its att tile, so
// pre-zeroing is dead work). prep is back to the original 512x128 MLP-only kernel
// with bit-identical reduction order (preserves absmax==0.0).
__global__ __launch_bounds__(128) void prep_kernel(
    const float* __restrict__ memory, const float* __restrict__ w1,
    const float* __restrict__ b1, const float* __restrict__ w2,
    const float* __restrict__ b2,
    _Float16* __restrict__ mN, float* __restrict__ mN32)
{
  __shared__ float sm[256];
  __shared__ float sh[128];
  __shared__ float s_part[2];
  __shared__ float s_tot;
  const int r = blockIdx.x;   // 0..511
  const int t = threadIdx.x;  // 0..127

  sm[t]       = memory[r * C_DIM + t];
  sm[t + 128] = memory[r * C_DIM + t + 128];
  __syncthreads();
  float acc = b1[t];
#pragma unroll 8
  for (int c = 0; c < 256; ++c) acc = fmaf(sm[c], w1[c * 128 + t], acc);
  sh[t] = fmaxf(acc, 0.f);
  __syncthreads();
  float o0 = b2[t], o1 = b2[t + 128];
#pragma unroll 8
  for (int k = 0; k < 128; ++k) {
    float h = sh[k];
    o0 = fmaf(h, w2[k * 256 + t], o0);
    o1 = fmaf(h, w2[k * 256 + t + 128], o1);
  }
  o0 = fmaxf(o0, 0.f);
  o1 = fmaxf(o1, 0.f);
  float ss = o0 * o0 + o1 * o1;
#pragma unroll
  for (int off = 32; off >= 1; off >>= 1) ss += __shfl_down(ss, off);
  if ((t & 63) == 0) s_part[t >> 6] = ss;
  __syncthreads();
  if (t == 0) s_tot = s_part[0] + s_part[1];
  __syncthreads();
  const float inv = 1.f / fmaxf(sqrtf(s_tot), 1e-12f);
  const float v0 = o0 * inv, v1 = o1 * inv;
  mN[r * C_DIM + t]        = (_Float16)v0;
  mN[r * C_DIM + t + 128]  = (_Float16)v1;
  mN32[r * C_DIM + t]       = v0;
  mN32[r * C_DIM + t + 128] = v1;
}

#define MFMA16(a, b, c) __builtin_amdgcn_mfma_f32_16x16x32_f16(a, b, c, 0, 0, 0)

// ---------------- fused main kernel: 32 pixels per block, 2048 blocks ----------------
// R11: 32-px tile -> acc[2][4] = 32 AGPR, 20.5 KB LDS, __launch_bounds__(512,6):
// 3 blocks/CU (24 waves/CU) vs R10's 2; main dropped below 120 us.
// R12: dense att_map store. At the normalize step each thread holds acc[mt][nt] =
// 4 CONSECUTIVE m-values (m = mt*16+q*4+r) at fixed n -> one aligned float4 of
// attmap[n][hw0+...]. 8 nontemporal float4 stores/thread cover the whole
// [512 n][32 m] tile exactly once (4 lanes x 16 B = 64 B contiguous segments =
// full cache-line writes). Replaces pre-zero fill (134 MB in prep) + sparse
// scatter; values bit-identical incl. +0.0f non-survivors.
__global__ __launch_bounds__(512, 6) void main_kernel(
    const float* __restrict__ x,
    const _Float16* __restrict__ mN,
    const float* __restrict__ mN32,
    float* __restrict__ out, float* __restrict__ attmap)
{
  __shared__ _Float16       Xh[32][264];       // 16896 B
  __shared__ unsigned short s_lslot[32][LCAP]; // 1024 B
  __shared__ float          s_lval[32][LCAP];  // 2048 B
  __shared__ int      s_cnt[32];
  __shared__ float    s_sumsq[32];
  __shared__ float    s_sum1[32];
  __shared__ float    s_sum2[32];               // total 20480 B

  const int tid  = threadIdx.x;
  const int wave = tid >> 6;     // 0..7
  const int lane = tid & 63;
  const int q    = lane >> 4;    // quad within wave
  const int c16  = lane & 15;
  const int g    = tid >> 3;     // 0..63: channel quad for phase A
  const int pxq  = tid & 7;      // pixel quad for phase A

  const int blk = blockIdx.x;          // 2048 blocks
  const int img = blk >> 7;            // 128 blocks per image
  const int hw0 = (blk & 127) * 32;
  const float* __restrict__ xb = x + (size_t)img * C_DIM * HW + hw0;

  if (tid < 32) {
    s_sumsq[tid] = 0.f; s_sum1[tid] = 0.f; s_sum2[tid] = 0.f; s_cnt[tid] = 0;
  }
  __syncthreads();  // B0

  // ---- Phase A: float4 loads (4 ch x 4 px per thread), fp16 pack, sumsq
  {
    floatx4 v[4];
#pragma unroll
    for (int i = 0; i < 4; ++i)
      v[i] = *(const floatx4*)(xb + (size_t)(4 * g + i) * HW + pxq * 4);
    float ps[4];
#pragma unroll
    for (int j = 0; j < 4; ++j) {
      const int p = pxq * 4 + j;
      half4v hv = {(_Float16)v[0][j], (_Float16)v[1][j], (_Float16)v[2][j], (_Float16)v[3][j]};
      *(half4v*)&Xh[p][4 * g] = hv;
      ps[j] = v[0][j] * v[0][j] + v[1][j] * v[1][j] + v[2][j] * v[2][j] + v[3][j] * v[3][j];
    }
#pragma unroll
    for (int off = 8; off < 64; off <<= 1)
#pragma unroll
      for (int j = 0; j < 4; ++j) ps[j] += __shfl_xor(ps[j], off);
    if ((lane >> 3) == 0) {
#pragma unroll
      for (int j = 0; j < 4; ++j) atomicAdd(&s_sumsq[4 * (lane & 7) + j], ps[j]);
    }
  }

  // B base pointers (kb offsets fold into the 13-bit imm: kb*32 halves = 64..448 B)
  const _Float16* bp[4];
#pragma unroll
  for (int nt = 0; nt < 4; ++nt)
    bp[nt] = mN + (size_t)(wave * 64 + nt * 16 + c16) * C_DIM + q * 8;

  __syncthreads();  // B1: Xh + sumsq ready

  // ---- Phase B: GEMM1  S[32][512] = Xh @ mN^T  (fp16 MFMA)
  floatx4 acc[2][4];
#pragma unroll
  for (int mt = 0; mt < 2; ++mt)
#pragma unroll
    for (int nt = 0; nt < 4; ++nt) {
      floatx4 z = {0.f, 0.f, 0.f, 0.f};
      acc[mt][nt] = z;
    }
#pragma unroll
  for (int kb = 0; kb < 8; ++kb) {
    half8 bv[4];
#pragma unroll
    for (int nt = 0; nt < 4; ++nt) bv[nt] = *(const half8*)(bp[nt] + kb * 32);
    const int k0 = kb * 32 + q * 8;
    half8 a0 = *(const half8*)&Xh[c16][k0];
    half8 a1 = *(const half8*)&Xh[16 + c16][k0];
#pragma unroll
    for (int nt = 0; nt < 4; ++nt) {
      acc[0][nt] = MFMA16(a0, bv[nt], acc[0][nt]);
      acc[1][nt] = MFMA16(a1, bv[nt], acc[1][nt]);
    }
  }

  // ---- Phase C: scale by 1/||x||, exp (cosines in [-1,1], no max shift needed)
  // C/D layout: value (m = mt*16 + q*4 + r, n = wave*64 + nt*16 + c16)
#pragma unroll
  for (int mt = 0; mt < 2; ++mt)
#pragma unroll
    for (int r = 0; r < 4; ++r) {
      const int m = mt * 16 + q * 4 + r;
      const float iv = 1.f / fmaxf(sqrtf(s_sumsq[m]), 1e-12f);
      float s = 0.f;
#pragma unroll
      for (int nt = 0; nt < 4; ++nt) {
        const float e = __expf(acc[mt][nt][r] * iv);
        acc[mt][nt][r] = e;
        s += e;
      }
      s += __shfl_xor(s, 1);
      s += __shfl_xor(s, 2);
      s += __shfl_xor(s, 4);
      s += __shfl_xor(s, 8);
      if (c16 == 0) atomicAdd(&s_sum1[m], s);
    }
  __syncthreads();  // B2: softmax denominators ready

  // t = relu(p - tau); row sum of t
#pragma unroll
  for (int mt = 0; mt < 2; ++mt)
#pragma unroll
    for (int r = 0; r < 4; ++r) {
      const int m = mt * 16 + q * 4 + r;
      const float isum = 1.f / s_sum1[m];
      float s = 0.f;
#pragma unroll
      for (int nt = 0; nt < 4; ++nt) {
        const float tv = fmaxf(acc[mt][nt][r] * isum - TAU, 0.f);
        acc[mt][nt][r] = tv;
        s += tv;
      }
      s += __shfl_xor(s, 1);
      s += __shfl_xor(s, 2);
      s += __shfl_xor(s, 4);
      s += __shfl_xor(s, 8);
      if (c16 == 0) atomicAdd(&s_sum2[m], s);
    }
  __syncthreads();  // B3: shrink sums ready

  // ---- normalize att in regs; DENSE nontemporal float4 store of the whole tile
  //      (replaces pre-zero + scatter); emit nonzeros to per-pixel LDS lists.
#pragma unroll
  for (int mt = 0; mt < 2; ++mt) {
    float rs[4];
#pragma unroll
    for (int r = 0; r < 4; ++r)
      rs[r] = 1.f / fmaxf(s_sum2[mt * 16 + q * 4 + r], 1e-12f);
#pragma unroll
    for (int nt = 0; nt < 4; ++nt) {
      floatx4 a4 = acc[mt][nt];
      const unsigned n = wave * 64 + nt * 16 + c16;
#pragma unroll
      for (int r = 0; r < 4; ++r) {
        a4[r] *= rs[r];
        if (a4[r] > 0.f) {
          const int m = mt * 16 + q * 4 + r;
          const int idx = atomicAdd(&s_cnt[m], 1);
          if (idx < LCAP) {
            s_lslot[m][idx] = (unsigned short)n;
            s_lval[m][idx]  = a4[r];
          }
        }
      }
      __builtin_nontemporal_store(
          a4, (floatx4*)(attmap + ((size_t)img * M_DIM + n) * HW + hw0 + mt * 16 + q * 4));
    }
  }
  __syncthreads();  // B4: lists ready

  // ---- sparse gather: thread owns 4 consecutive pixels x 4 channels.
  // All loads precede all stores (R6 lesson).
  const int px4 = (tid & 7) * 4;    // pixels px4..px4+3
  const int chg = tid >> 3;         // 0..63 -> channels [4*chg, 4*chg+4)
  floatx4 f[4] = {{0.f,0.f,0.f,0.f},{0.f,0.f,0.f,0.f},{0.f,0.f,0.f,0.f},{0.f,0.f,0.f,0.f}};
#pragma unroll
  for (int p = 0; p < 4; ++p) {
    const int cn = min(s_cnt[px4 + p], LCAP);
    for (int j = 0; j < cn; ++j) {
      const int slot  = s_lslot[px4 + p][j];
      const float v   = s_lval[px4 + p][j];
      const floatx4 r0 = *(const floatx4*)(mN32 + (size_t)slot * C_DIM + chg * 4);
      f[0][p] += v * r0[0]; f[1][p] += v * r0[1];
      f[2][p] += v * r0[2]; f[3][p] += v * r0[3];
    }
  }

  // ---- out stores: float4 per (channel, 4-px group); nontemporal (write-once)
#pragma unroll
  for (int c = 0; c < 4; ++c)
    __builtin_nontemporal_store(
        f[c], (floatx4*)(out + ((size_t)img * C_DIM + chg * 4 + c) * HW + hw0 + px4));
}

extern "C" void kernel_launch(void* const* d_in, const int* in_sizes, int n_in,
                              void* d_out, int out_size, void* d_ws, size_t ws_size,
                              hipStream_t stream) {
  (void)in_sizes; (void)n_in; (void)out_size; (void)ws_size;
  const float* x      = (const float*)d_in[0];
  const float* memory = (const float*)d_in[1];
  const float* w1     = (const float*)d_in[2];
  const float* b1     = (const float*)d_in[3];
  const float* w2     = (const float*)d_in[4];
  const float* b2     = (const float*)d_in[5];
  float* out    = (float*)d_out;
  float* attmap = out + (size_t)16 * C_DIM * HW;  // output first, att_map second

  _Float16* mN   = (_Float16*)d_ws;
  float*    mN32 = (float*)((char*)d_ws + (size_t)M_DIM * C_DIM * sizeof(_Float16));

  hipLaunchKernelGGL(prep_kernel, dim3(M_DIM), dim3(128), 0, stream,
                     memory, w1, b1, w2, b2, mN, mN32);
  hipLaunchKernelGGL(main_kernel, dim3(2048), dim3(512), 0, stream,
                     x, mN, mN32, out, attmap);
}